// Round 5
// baseline (1210.195 us; speedup 1.0000x reference)
//
#include <hip/hip_runtime.h>

#define H    128
#define RBF  50
#define K1   64     // stage-1 K padded 50 -> 64
#define EB   64     // edges per tile
#define NB   32
#define NBLK 768    // 3 blocks/CU exactly

typedef _Float16 f16;
typedef _Float16 f16x4 __attribute__((ext_vector_type(4)));
typedef _Float16 f16x8 __attribute__((ext_vector_type(8)));
typedef float    f32x4 __attribute__((ext_vector_type(4)));

// LDS strides (f16/f32 elems)
#define EA_LD  104   // f16, 208B rows
#define T_LD   136   // f16, 272B rows
#define MSG_LD 132   // f32, 528B rows (528%64=16 -> row-major reduce reads conflict-free)
#define HS_LD  136   // f16, 272B rows (16B-aligned b128 writes)

__device__ __forceinline__ float silu_f(float a) {
    return a / (1.0f + __expf(-a));
}

// ---------------- CSR build ----------------

__global__ __launch_bounds__(256) void hist_kernel(
    const int* __restrict__ dst, int* __restrict__ counts, int E)
{
    for (int i = blockIdx.x * 256 + threadIdx.x; i < E; i += gridDim.x * 256)
        atomicAdd(&counts[dst[i]], 1);
}

__global__ __launch_bounds__(256) void scan1_kernel(
    const int* __restrict__ counts, int* __restrict__ ofs, int* __restrict__ bsum, int N)
{
    __shared__ int s[256];
    const int t = threadIdx.x;
    const int g = blockIdx.x * 256 + t;
    int v = (g < N) ? counts[g] : 0;
    s[t] = v; __syncthreads();
    for (int off = 1; off < 256; off <<= 1) {
        int u = 0; if (t >= off) u = s[t - off];
        __syncthreads(); s[t] += u; __syncthreads();
    }
    if (g < N) ofs[g] = s[t] - v;
    if (t == 255) bsum[blockIdx.x] = s[255];
}
__global__ __launch_bounds__(256) void scan2_kernel(int* __restrict__ bsum, int nb)
{
    __shared__ int s[256];
    const int t = threadIdx.x;
    int v = (t < nb) ? bsum[t] : 0;
    s[t] = v; __syncthreads();
    for (int off = 1; off < 256; off <<= 1) {
        int u = 0; if (t >= off) u = s[t - off];
        __syncthreads(); s[t] += u; __syncthreads();
    }
    if (t < nb) bsum[t] = s[t] - v;
}
__global__ __launch_bounds__(256) void scan3_kernel(
    int* __restrict__ ofs, const int* __restrict__ bsum, int N)
{
    int g = blockIdx.x * 256 + threadIdx.x;
    if (g < N) ofs[g] += bsum[blockIdx.x];
}

// block ranges cut at node boundaries near b*E/B edges
__global__ __launch_bounds__(256) void ranges_kernel(
    const int* __restrict__ ofs, int* __restrict__ nstart, int* __restrict__ estart,
    int N, int E, int B)
{
    int b = blockIdx.x * 256 + threadIdx.x;
    if (b > B) return;
    if (b == B) { nstart[B] = N; estart[B] = E; return; }
    long long cb = (long long)b * E / B;
    int lo = 0, hi = N;
    while (lo < hi) {
        int mid = (lo + hi) >> 1;
        int val = (mid < N) ? ofs[mid] : E;
        if (val < (int)cb) lo = mid + 1; else hi = mid;
    }
    nstart[b] = lo;
    estart[b] = (lo < N) ? ofs[lo] : E;
}

// rec[pos] = {e, src[e], dst[e], 0} at dst-sorted pos  (destroys cursor=ofs)
__global__ __launch_bounds__(256) void scatter_rec_kernel(
    const int* __restrict__ src, const int* __restrict__ dst,
    int* __restrict__ cursor, int4* __restrict__ rec, int E)
{
    for (int i = blockIdx.x * 256 + threadIdx.x; i < E; i += gridDim.x * 256) {
        int d = dst[i];
        int pos = atomicAdd(&cursor[d], 1);
        rec[pos] = make_int4(i, src[i], d, 0);
    }
}

// ---------------- weight convert + h ----------------

__global__ __launch_bounds__(256) void convert_weights_kernel(
    const float* __restrict__ fW1, const float* __restrict__ fW2,
    f16* __restrict__ Wt1, f16* __restrict__ Wt2)
{
    int i = blockIdx.x * 256 + threadIdx.x;
    if (i < H * K1) {
        int n = i >> 6, k = i & (K1 - 1);
        Wt1[i] = (k < RBF) ? (f16)fW1[k * H + n] : (f16)0.f;
    }
    int j = i - H * K1;
    if (j >= 0 && j < H * H) {
        int n = j >> 7, k = j & (H - 1);
        Wt2[j] = (f16)fW2[k * H + n];
    }
}

__global__ __launch_bounds__(256) void compute_h_kernel(
    const float* __restrict__ x, const float* __restrict__ dW,
    const float* __restrict__ db, f16* __restrict__ h, int N)
{
    __shared__ float xs[NB][H];
    const int tid = threadIdx.x;
    const int n0  = blockIdx.x * NB;
    for (int idx = tid; idx < NB * H; idx += 256) {
        int r = idx >> 7, c = idx & (H - 1);
        int n = n0 + r;
        xs[r][c] = (n < N) ? x[(size_t)n * H + c] : 0.f;
    }
    __syncthreads();
    const int j  = tid & (H - 1);
    const int rb = (tid >> 7) * 16;
    float acc[16];
    const float b = db[j];
#pragma unroll
    for (int r = 0; r < 16; ++r) acc[r] = b;
    for (int kq = 0; kq < H / 4; ++kq) {
        const int k = kq * 4;
        const float w0 = dW[(k + 0) * H + j];
        const float w1 = dW[(k + 1) * H + j];
        const float w2 = dW[(k + 2) * H + j];
        const float w3 = dW[(k + 3) * H + j];
#pragma unroll
        for (int r = 0; r < 16; ++r) {
            const float4 v = *(const float4*)&xs[rb + r][k];
            acc[r] = fmaf(v.x, w0, fmaf(v.y, w1, fmaf(v.z, w2, fmaf(v.w, w3, acc[r]))));
        }
    }
#pragma unroll
    for (int r = 0; r < 16; ++r) {
        int n = n0 + rb + r;
        if (n < N) h[(size_t)n * H + j] = (f16)acc[r];
    }
}

// ---------------- fused edge kernel: direct ea gather, sector-exact h gather ----------------
__global__ __launch_bounds__(256, 3) void edge_fused_kernel(
    const float* __restrict__ ea, const int4* __restrict__ rec,
    const f16* __restrict__ Wt1, const f16* __restrict__ Wt2,
    const float* __restrict__ fb1, const float* __restrict__ fb2,
    const f16* __restrict__ h, float* __restrict__ out,
    const int* __restrict__ nstart, const int* __restrict__ estart)
{
    union SharedU {
        struct { f16 ea[EB][EA_LD]; f16 t[EB][T_LD]; } s;
        float msg[EB][MSG_LD];
    };
    __shared__ __align__(16) SharedU u;
    __shared__ __align__(16) f16 h_s[EB][HS_LD];
    __shared__ int dst_s[EB];

    const int tid  = threadIdx.x;
    const int lane = tid & 63;
    const int wv   = tid >> 6;
    const int wr   = (wv >> 1) * 32;
    const int wc   = (wv & 1) * 64;
    const int fr   = lane & 15;
    const int qw   = lane >> 4;
    const int kb   = qw * 8;

    // persistent B fragments
    f16x8 B1[4][2];
    f16x8 B2[4][4];
    float b1v[4], b2v[4];
#pragma unroll
    for (int ct = 0; ct < 4; ++ct) {
        const int col = wc + ct * 16 + fr;
#pragma unroll
        for (int ks = 0; ks < 2; ++ks)
            B1[ct][ks] = *(const f16x8*)&Wt1[col * K1 + ks * 32 + kb];
#pragma unroll
        for (int ks = 0; ks < 4; ++ks)
            B2[ct][ks] = *(const f16x8*)&Wt2[col * H + ks * 32 + kb];
        b1v[ct] = fb1[col];
        b2v[ct] = fb2[col];
    }

    const int ns = nstart[blockIdx.x], ne = nstart[blockIdx.x + 1];
    const int e0 = estart[blockIdx.x], e1 = estart[blockIdx.x + 1];

    const int col128 = tid & 127;
    const int gr = tid & 63;    // h-gather row
    const int gg = tid >> 6;    // h-gather 64B segment
    int   curdst = ns;
    float accv   = 0.f;

    for (int tb = e0; tb < e1; tb += EB) {
        const int nrows = min(EB, e1 - tb);
        __syncthreads();   // prev tile's msg reads done before restaging

        // ---- hoisted sector-exact h gather: 64B of one row per thread ----
        f16x8 hreg[4];
        {
            const int sr = (gr < nrows) ? rec[tb + gr].y : 0;
            const f16* hp = h + (size_t)sr * H + gg * 32;
#pragma unroll
            for (int k2 = 0; k2 < 4; ++k2) hreg[k2] = *(const f16x8*)(hp + k2 * 8);
        }

        // ---- stage ea rows (direct f32 gather -> f16 LDS), 16 slots/row of 4 cols ----
#pragma unroll
        for (int it = 0; it < 4; ++it) {
            const int idx = tid + it * 256;
            const int r = idx >> 4, q = idx & 15;
            f16x4 o = {};
            if (r < nrows) {
                const float* rp = ea + (size_t)rec[tb + r].x * RBF;
                if (q < 12) {
                    const float4 v = *(const float4*)(rp + q * 4);
                    o[0] = (f16)v.x; o[1] = (f16)v.y; o[2] = (f16)v.z; o[3] = (f16)v.w;
                } else if (q == 12) {
                    const float2 v = *(const float2*)(rp + 48);
                    o[0] = (f16)v.x; o[1] = (f16)v.y;
                }
            }
            *(f16x4*)&u.s.ea[r][q * 4] = o;
        }
        if (tid < EB) dst_s[tid] = (tid < nrows) ? rec[tb + tid].z : ne;
        __syncthreads();

        // ---- stage 1: t = ea @ W1 + b1 ----
        f32x4 acc[2][4];
#pragma unroll
        for (int rt = 0; rt < 2; ++rt)
#pragma unroll
            for (int ct = 0; ct < 4; ++ct)
                acc[rt][ct] = (f32x4){b1v[ct], b1v[ct], b1v[ct], b1v[ct]};
#pragma unroll
        for (int ks = 0; ks < 2; ++ks) {
            const f16x8 A0 = *(const f16x8*)&u.s.ea[wr + fr][ks * 32 + kb];
            const f16x8 A1 = *(const f16x8*)&u.s.ea[wr + 16 + fr][ks * 32 + kb];
#pragma unroll
            for (int ct = 0; ct < 4; ++ct) {
                acc[0][ct] = __builtin_amdgcn_mfma_f32_16x16x32_f16(A0, B1[ct][ks], acc[0][ct], 0, 0, 0);
                acc[1][ct] = __builtin_amdgcn_mfma_f32_16x16x32_f16(A1, B1[ct][ks], acc[1][ct], 0, 0, 0);
            }
        }

        // ---- silu -> t (f16) ----
#pragma unroll
        for (int rt = 0; rt < 2; ++rt)
#pragma unroll
            for (int ct = 0; ct < 4; ++ct)
#pragma unroll
                for (int m = 0; m < 4; ++m) {
                    const int row = wr + rt * 16 + qw * 4 + m;
                    const int c   = wc + ct * 16 + fr;
                    u.s.t[row][c] = (f16)silu_f(acc[rt][ct][m]);
                }
        __syncthreads();

        // ---- stage 2: filters = t @ W2 + b2 ----
        f32x4 acc2[2][4];
#pragma unroll
        for (int rt = 0; rt < 2; ++rt)
#pragma unroll
            for (int ct = 0; ct < 4; ++ct)
                acc2[rt][ct] = (f32x4){b2v[ct], b2v[ct], b2v[ct], b2v[ct]};
#pragma unroll
        for (int ks = 0; ks < 4; ++ks) {
            const f16x8 A0 = *(const f16x8*)&u.s.t[wr + fr][ks * 32 + kb];
            const f16x8 A1 = *(const f16x8*)&u.s.t[wr + 16 + fr][ks * 32 + kb];
#pragma unroll
            for (int ct = 0; ct < 4; ++ct) {
                acc2[0][ct] = __builtin_amdgcn_mfma_f32_16x16x32_f16(A0, B2[ct][ks], acc2[0][ct], 0, 0, 0);
                acc2[1][ct] = __builtin_amdgcn_mfma_f32_16x16x32_f16(A1, B2[ct][ks], acc2[1][ct], 0, 0, 0);
            }
        }
        __syncthreads();   // t reads done before msg overlays

        // ---- redistribute h via LDS ----
#pragma unroll
        for (int k2 = 0; k2 < 4; ++k2)
            *(f16x8*)&h_s[gr][gg * 32 + k2 * 8] = hreg[k2];
        __syncthreads();

        // ---- msg = h * filt -> LDS (f32) ----
#pragma unroll
        for (int rt = 0; rt < 2; ++rt)
#pragma unroll
            for (int ct = 0; ct < 4; ++ct)
#pragma unroll
                for (int m = 0; m < 4; ++m) {
                    const int er = wr + rt * 16 + qw * 4 + m;
                    const int c  = wc + ct * 16 + fr;
                    u.msg[er][c] = (float)h_s[er][c] * acc2[rt][ct][m];
                }
        __syncthreads();

        // ---- sequential segmented reduce: exclusive node range, plain stores ----
        if (tid < 128) {
            for (int r = 0; r < EB; ++r) {
                const int d = dst_s[r];
                if (d != curdst) {
                    out[(size_t)curdst * H + col128] = accv;
                    for (int n = curdst + 1; n < d; ++n) out[(size_t)n * H + col128] = 0.f;
                    curdst = d; accv = 0.f;
                }
                if (d < ne) accv += u.msg[r][col128];
            }
        }
    }
    if (tid < 128 && curdst < ne) {
        out[(size_t)curdst * H + col128] = accv;
        for (int n = curdst + 1; n < ne; ++n) out[(size_t)n * H + col128] = 0.f;
    }
}

// out = x + silu(agg@uW1+ub1)@uW2+ub2 ; agg lives in `out` on entry
__global__ __launch_bounds__(256) void update_kernel(
    const float* __restrict__ x,
    const float* __restrict__ uW1, const float* __restrict__ ub1,
    const float* __restrict__ uW2, const float* __restrict__ ub2,
    float* __restrict__ out, int N)
{
    __shared__ float as[NB][H];
    __shared__ float ts[NB][H];
    const int tid = threadIdx.x;
    const int n0  = blockIdx.x * NB;
    for (int idx = tid; idx < NB * H; idx += 256) {
        int r = idx >> 7, c = idx & (H - 1);
        int n = n0 + r;
        as[r][c] = (n < N) ? out[(size_t)n * H + c] : 0.f;
    }
    __syncthreads();
    const int j  = tid & (H - 1);
    const int rb = (tid >> 7) * 16;
    float acc[16];
    {
        const float b1 = ub1[j];
#pragma unroll
        for (int r = 0; r < 16; ++r) acc[r] = b1;
    }
    for (int kq = 0; kq < H / 4; ++kq) {
        const int k = kq * 4;
        const float w0 = uW1[(k + 0) * H + j];
        const float w1 = uW1[(k + 1) * H + j];
        const float w2 = uW1[(k + 2) * H + j];
        const float w3 = uW1[(k + 3) * H + j];
#pragma unroll
        for (int r = 0; r < 16; ++r) {
            const float4 v = *(const float4*)&as[rb + r][k];
            acc[r] = fmaf(v.x, w0, fmaf(v.y, w1, fmaf(v.z, w2, fmaf(v.w, w3, acc[r]))));
        }
    }
#pragma unroll
    for (int r = 0; r < 16; ++r) ts[rb + r][j] = silu_f(acc[r]);
    __syncthreads();
    {
        const float b2 = ub2[j];
#pragma unroll
        for (int r = 0; r < 16; ++r) acc[r] = b2;
    }
    for (int kq = 0; kq < H / 4; ++kq) {
        const int k = kq * 4;
        const float w0 = uW2[(k + 0) * H + j];
        const float w1 = uW2[(k + 1) * H + j];
        const float w2 = uW2[(k + 2) * H + j];
        const float w3 = uW2[(k + 3) * H + j];
#pragma unroll
        for (int r = 0; r < 16; ++r) {
            const float4 v = *(const float4*)&ts[rb + r][k];
            acc[r] = fmaf(v.x, w0, fmaf(v.y, w1, fmaf(v.z, w2, fmaf(v.w, w3, acc[r]))));
        }
    }
#pragma unroll
    for (int r = 0; r < 16; ++r) {
        int n = n0 + rb + r;
        if (n < N) out[(size_t)n * H + j] = x[(size_t)n * H + j] + acc[r];
    }
}

extern "C" void kernel_launch(void* const* d_in, const int* in_sizes, int n_in,
                              void* d_out, int out_size, void* d_ws, size_t ws_size,
                              hipStream_t stream) {
    const float* x   = (const float*)d_in[0];
    const int*   ei  = (const int*)  d_in[1];
    const float* ea  = (const float*)d_in[2];
    const float* fW1 = (const float*)d_in[3];
    const float* fb1 = (const float*)d_in[4];
    const float* fW2 = (const float*)d_in[5];
    const float* fb2 = (const float*)d_in[6];
    const float* dW  = (const float*)d_in[7];
    const float* db  = (const float*)d_in[8];
    const float* uW1 = (const float*)d_in[9];
    const float* ub1 = (const float*)d_in[10];
    const float* uW2 = (const float*)d_in[11];
    const float* ub2 = (const float*)d_in[12];

    float* out = (float*)d_out;
    const int N = in_sizes[0] / H;
    const int E = in_sizes[1] / 2;
    const int* src = ei;
    const int* dst = ei + E;

    // workspace (~39 MB; >=327 MB proven in R4)
    char* ws = (char*)d_ws;
    size_t off = 0;
    auto alloc = [&](size_t bytes) { void* p = ws + off; off = (off + bytes + 255) & ~(size_t)255; return p; };
    f16*  h      = (f16*) alloc((size_t)N * H * sizeof(f16));
    f16*  Wt1    = (f16*) alloc((size_t)H * K1 * sizeof(f16));
    f16*  Wt2    = (f16*) alloc((size_t)H * H * sizeof(f16));
    int*  counts = (int*) alloc((size_t)N * sizeof(int));
    int*  ofs    = (int*) alloc((size_t)N * sizeof(int));    // becomes scatter cursor
    int*  bsum   = (int*) alloc(256 * sizeof(int));
    int*  nstart = (int*) alloc((size_t)(NBLK + 1) * sizeof(int));
    int*  estart = (int*) alloc((size_t)(NBLK + 1) * sizeof(int));
    int4* rec    = (int4*)alloc((size_t)E * sizeof(int4));

    const int nscan = (N + 255) / 256;   // 196 <= 256

    hipMemsetAsync(counts, 0, (size_t)N * sizeof(int), stream);
    convert_weights_kernel<<<(H * K1 + H * H + 255) / 256, 256, 0, stream>>>(fW1, fW2, Wt1, Wt2);
    compute_h_kernel<<<(N + NB - 1) / NB, 256, 0, stream>>>(x, dW, db, h, N);

    hist_kernel<<<1024, 256, 0, stream>>>(dst, counts, E);
    scan1_kernel<<<nscan, 256, 0, stream>>>(counts, ofs, bsum, N);
    scan2_kernel<<<1, 256, 0, stream>>>(bsum, nscan);
    scan3_kernel<<<nscan, 256, 0, stream>>>(ofs, bsum, N);

    ranges_kernel<<<(NBLK + 256) / 256, 256, 0, stream>>>(ofs, nstart, estart, N, E, NBLK);
    scatter_rec_kernel<<<1024, 256, 0, stream>>>(src, dst, ofs, rec, E);

    edge_fused_kernel<<<NBLK, 256, 0, stream>>>(
        ea, rec, Wt1, Wt2, fb1, fb2, h, out, nstart, estart);

    update_kernel<<<(N + NB - 1) / NB, 256, 0, stream>>>(
        x, uW1, ub1, uW2, ub2, out, N);
}

// Round 6
// 1132.295 us; speedup vs baseline: 1.0688x; 1.0688x over previous
//
#include <hip/hip_runtime.h>

#define H    128
#define RBF  50
#define K1   64     // stage-1 K padded 50 -> 64
#define EB   64     // edges per tile
#define NB   32
#define NBLK 1024   // 4 blocks/CU exactly

typedef _Float16 f16;
typedef _Float16 f16x2 __attribute__((ext_vector_type(2)));
typedef _Float16 f16x4 __attribute__((ext_vector_type(4)));
typedef _Float16 f16x8 __attribute__((ext_vector_type(8)));
typedef float    f32x4 __attribute__((ext_vector_type(4)));

#define HS_LD 132   // h_s row stride (f16): 264B -> reduce column-walk 2-way (free)

__device__ __forceinline__ float silu_f(float a) {
    return a / (1.0f + __expf(-a));
}

// ---------------- CSR build ----------------

__global__ __launch_bounds__(256) void hist_kernel(
    const int* __restrict__ dst, int* __restrict__ counts, int E)
{
    for (int i = blockIdx.x * 256 + threadIdx.x; i < E; i += gridDim.x * 256)
        atomicAdd(&counts[dst[i]], 1);
}

__global__ __launch_bounds__(256) void scan1_kernel(
    const int* __restrict__ counts, int* __restrict__ ofs, int* __restrict__ bsum, int N)
{
    __shared__ int s[256];
    const int t = threadIdx.x;
    const int g = blockIdx.x * 256 + t;
    int v = (g < N) ? counts[g] : 0;
    s[t] = v; __syncthreads();
    for (int off = 1; off < 256; off <<= 1) {
        int u = 0; if (t >= off) u = s[t - off];
        __syncthreads(); s[t] += u; __syncthreads();
    }
    if (g < N) ofs[g] = s[t] - v;
    if (t == 255) bsum[blockIdx.x] = s[255];
}
__global__ __launch_bounds__(256) void scan2_kernel(int* __restrict__ bsum, int nb)
{
    __shared__ int s[256];
    const int t = threadIdx.x;
    int v = (t < nb) ? bsum[t] : 0;
    s[t] = v; __syncthreads();
    for (int off = 1; off < 256; off <<= 1) {
        int u = 0; if (t >= off) u = s[t - off];
        __syncthreads(); s[t] += u; __syncthreads();
    }
    if (t < nb) bsum[t] = s[t] - v;
}
__global__ __launch_bounds__(256) void scan3_kernel(
    int* __restrict__ ofs, const int* __restrict__ bsum, int N)
{
    int g = blockIdx.x * 256 + threadIdx.x;
    if (g < N) ofs[g] += bsum[blockIdx.x];
}

// block ranges cut at node boundaries near b*E/B edges
__global__ __launch_bounds__(256) void ranges_kernel(
    const int* __restrict__ ofs, int* __restrict__ nstart, int* __restrict__ estart,
    int N, int E, int B)
{
    int b = blockIdx.x * 256 + threadIdx.x;
    if (b > B) return;
    if (b == B) { nstart[B] = N; estart[B] = E; return; }
    long long cb = (long long)b * E / B;
    int lo = 0, hi = N;
    while (lo < hi) {
        int mid = (lo + hi) >> 1;
        int val = (mid < N) ? ofs[mid] : E;
        if (val < (int)cb) lo = mid + 1; else hi = mid;
    }
    nstart[b] = lo;
    estart[b] = (lo < N) ? ofs[lo] : E;
}

// rec[pos] = {e, src[e], dst[e], 0} at dst-sorted pos  (destroys cursor=ofs)
__global__ __launch_bounds__(256) void scatter_rec_kernel(
    const int* __restrict__ src, const int* __restrict__ dst,
    int* __restrict__ cursor, int4* __restrict__ rec, int E)
{
    for (int i = blockIdx.x * 256 + threadIdx.x; i < E; i += gridDim.x * 256) {
        int d = dst[i];
        int pos = atomicAdd(&cursor[d], 1);
        rec[pos] = make_int4(i, src[i], d, 0);
    }
}

// ---------------- weight convert + h ----------------

__global__ __launch_bounds__(256) void convert_weights_kernel(
    const float* __restrict__ fW1, const float* __restrict__ fW2,
    f16* __restrict__ Wt1, f16* __restrict__ Wt2)
{
    int i = blockIdx.x * 256 + threadIdx.x;
    if (i < H * K1) {
        int n = i >> 6, k = i & (K1 - 1);
        Wt1[i] = (k < RBF) ? (f16)fW1[k * H + n] : (f16)0.f;
    }
    int j = i - H * K1;
    if (j >= 0 && j < H * H) {
        int n = j >> 7, k = j & (H - 1);
        Wt2[j] = (f16)fW2[k * H + n];
    }
}

__global__ __launch_bounds__(256) void compute_h_kernel(
    const float* __restrict__ x, const float* __restrict__ dW,
    const float* __restrict__ db, f16* __restrict__ h, int N)
{
    __shared__ float xs[NB][H];
    const int tid = threadIdx.x;
    const int n0  = blockIdx.x * NB;
    for (int idx = tid; idx < NB * H; idx += 256) {
        int r = idx >> 7, c = idx & (H - 1);
        int n = n0 + r;
        xs[r][c] = (n < N) ? x[(size_t)n * H + c] : 0.f;
    }
    __syncthreads();
    const int j  = tid & (H - 1);
    const int rb = (tid >> 7) * 16;
    float acc[16];
    const float b = db[j];
#pragma unroll
    for (int r = 0; r < 16; ++r) acc[r] = b;
    for (int kq = 0; kq < H / 4; ++kq) {
        const int k = kq * 4;
        const float w0 = dW[(k + 0) * H + j];
        const float w1 = dW[(k + 1) * H + j];
        const float w2 = dW[(k + 2) * H + j];
        const float w3 = dW[(k + 3) * H + j];
#pragma unroll
        for (int r = 0; r < 16; ++r) {
            const float4 v = *(const float4*)&xs[rb + r][k];
            acc[r] = fmaf(v.x, w0, fmaf(v.y, w1, fmaf(v.z, w2, fmaf(v.w, w3, acc[r]))));
        }
    }
#pragma unroll
    for (int r = 0; r < 16; ++r) {
        int n = n0 + rb + r;
        if (n < N) h[(size_t)n * H + j] = (f16)acc[r];
    }
}

// write one ea row-slice into A-frag-layout LDS: element (row j, col c) lives at
// byte ((c>>3)*64 + j)*16 + (c&7)*2.  Thread (j, s) holds cols {m*16+s*4..+4} + tail.
__device__ __forceinline__ void ea_frag_write(
    f16* uni, int j, int s,
    const float4& f0, const float4& f1, const float4& f2, const float2& f3)
{
    char* base = (char*)uni;
    {
        f16x4 v; v[0]=(f16)f0.x; v[1]=(f16)f0.y; v[2]=(f16)f0.z; v[3]=(f16)f0.w;
        *(f16x4*)(base + (size_t)(((0 + (s >> 1)) * 64 + j) * 16 + (s & 1) * 8)) = v;
    }
    {
        f16x4 v; v[0]=(f16)f1.x; v[1]=(f16)f1.y; v[2]=(f16)f1.z; v[3]=(f16)f1.w;
        *(f16x4*)(base + (size_t)(((2 + (s >> 1)) * 64 + j) * 16 + (s & 1) * 8)) = v;
    }
    {
        f16x4 v; v[0]=(f16)f2.x; v[1]=(f16)f2.y; v[2]=(f16)f2.z; v[3]=(f16)f2.w;
        *(f16x4*)(base + (size_t)(((4 + (s >> 1)) * 64 + j) * 16 + (s & 1) * 8)) = v;
    }
    if (s == 0) {
        char* b6 = base + (size_t)((6 * 64 + j) * 16);
        f16x2 v2; v2[0]=(f16)f3.x; v2[1]=(f16)f3.y;
        f16x2 z2 = {};
        *(f16x2*)(b6)      = v2;
        *(f16x2*)(b6 + 4)  = z2;
        *(f16x2*)(b6 + 8)  = z2;
        *(f16x2*)(b6 + 12) = z2;
    } else if (s == 1) {
        f16x8 z8 = {};
        *(f16x8*)(base + (size_t)((7 * 64 + j) * 16)) = z8;
    }
}

// ---------------- fused edge kernel: prefetched, sector-coalesced, zero atomics ----------------
__global__ __launch_bounds__(256, 4) void edge_fused_kernel(
    const float* __restrict__ ea, const int4* __restrict__ rec,
    const f16* __restrict__ Wt1, const f16* __restrict__ Wt2,
    const float* __restrict__ fb1, const float* __restrict__ fb2,
    const f16* __restrict__ h, float* __restrict__ out,
    const int* __restrict__ nstart, const int* __restrict__ estart)
{
    // uni: ea frags occupy [0,8192)B, t frags [0,16384)B (time-shared)
    __shared__ __align__(16) f16 uni[8192];
    __shared__ __align__(16) f16 h_s[EB * HS_LD];
    __shared__ int dst_s[2][EB];

    const int tid  = threadIdx.x;
    const int lane = tid & 63;
    const int wv   = tid >> 6;
    const int wr   = (wv >> 1) * 32;
    const int wc   = (wv & 1) * 64;
    const int fr   = lane & 15;
    const int qw   = lane >> 4;
    const int kb   = qw * 8;

    const int j = tid >> 2;   // gather row 0..63
    const int s = tid & 3;    // gather quarter

    // persistent B fragments
    f16x8 B1[4][2];
    f16x8 B2[4][4];
    float b1v[4], b2v[4];
#pragma unroll
    for (int ct = 0; ct < 4; ++ct) {
        const int col = wc + ct * 16 + fr;
#pragma unroll
        for (int ks = 0; ks < 2; ++ks)
            B1[ct][ks] = *(const f16x8*)&Wt1[col * K1 + ks * 32 + kb];
#pragma unroll
        for (int ks = 0; ks < 4; ++ks)
            B2[ct][ks] = *(const f16x8*)&Wt2[col * H + ks * 32 + kb];
        b1v[ct] = fb1[col];
        b2v[ct] = fb2[col];
    }

    const int ns = nstart[blockIdx.x], ne = nstart[blockIdx.x + 1];
    const int e0 = estart[blockIdx.x], e1 = estart[blockIdx.x + 1];

    if (e0 >= e1) {   // no edges: zero own node range
        for (int idx = tid; idx < (ne - ns) * H; idx += 256)
            out[(size_t)ns * H + idx] = 0.f;
        return;
    }

    // ---------------- prologue: prime tile 0 ----------------
    int4 recP, recN;
    f16x8 hP0, hP1, hP2, hP3, hN0, hN1, hN2, hN3;
    float4 ef0, ef1, ef2; float2 ef3 = {};

    {
        int idx = e0 + j; idx = (idx < e1) ? idx : (e1 - 1);
        recP = rec[idx];
    }
    {   // h(t0): 4 sector-grouped 16B loads (4 lanes per row within each inst)
        const f16* hp = h + (size_t)recP.y * H + s * 8;
        hP0 = *(const f16x8*)(hp);
        hP1 = *(const f16x8*)(hp + 32);
        hP2 = *(const f16x8*)(hp + 64);
        hP3 = *(const f16x8*)(hp + 96);
        const float* ep = ea + (size_t)recP.x * RBF + s * 4;
        ef0 = *(const float4*)(ep);
        ef1 = *(const float4*)(ep + 16);
        ef2 = *(const float4*)(ep + 32);
        if (s == 0) ef3 = *(const float2*)(ea + (size_t)recP.x * RBF + 48);
    }
    {
        int idx = e0 + EB + j; idx = (idx < e1) ? idx : (e1 - 1);
        recN = rec[idx];
    }
    if (s == 0) dst_s[0][j] = (e0 + j < e1) ? recP.z : ne;
    ea_frag_write(uni, j, s, ef0, ef1, ef2, ef3);
    __syncthreads();

    const int col128 = tid & 127;
    int   curdst = ns;
    float accv   = 0.f;
    int   cur    = 0;

    for (int tb = e0; tb < e1; tb += EB) {
        const int tb1 = tb + EB;

        // ---- phase 1: commit h(t) -> h_s ; dst(t+1) -> alt buffer ----
        *(f16x8*)&h_s[j * HS_LD +  0 + s * 8] = hP0;
        *(f16x8*)&h_s[j * HS_LD + 32 + s * 8] = hP1;
        *(f16x8*)&h_s[j * HS_LD + 64 + s * 8] = hP2;
        *(f16x8*)&h_s[j * HS_LD + 96 + s * 8] = hP3;
        if (s == 0) dst_s[cur ^ 1][j] = (tb1 + j < e1) ? recN.z : ne;

        // ---- phase 2-4: issue prefetches for t+2 (rec) and t+1 (h, ea) ----
        int4 recN2;
        {
            int idx = tb1 + EB + j; idx = (idx < e1) ? idx : (e1 - 1);
            recN2 = rec[idx];
        }
        {
            const f16* hp = h + (size_t)recN.y * H + s * 8;
            hN0 = *(const f16x8*)(hp);
            hN1 = *(const f16x8*)(hp + 32);
            hN2 = *(const f16x8*)(hp + 64);
            hN3 = *(const f16x8*)(hp + 96);
            const float* ep = ea + (size_t)recN.x * RBF + s * 4;
            ef0 = *(const float4*)(ep);
            ef1 = *(const float4*)(ep + 16);
            ef2 = *(const float4*)(ep + 32);
            if (s == 0) ef3 = *(const float2*)(ea + (size_t)recN.x * RBF + 48);
        }
        __syncthreads();   // B1: h_s visible

        // ---- stage 1 MFMA: t = ea @ W1 + b1  (A-frags conflict-free) ----
        f32x4 acc1[2][4];
#pragma unroll
        for (int rt = 0; rt < 2; ++rt)
#pragma unroll
            for (int ct = 0; ct < 4; ++ct)
                acc1[rt][ct] = (f32x4){b1v[ct], b1v[ct], b1v[ct], b1v[ct]};
#pragma unroll
        for (int ks = 0; ks < 2; ++ks) {
            const f16x8 A0 = *(const f16x8*)((char*)uni + (size_t)(((ks * 4 + qw) * 64 + wr + fr) * 16));
            const f16x8 A1 = *(const f16x8*)((char*)uni + (size_t)(((ks * 4 + qw) * 64 + wr + 16 + fr) * 16));
#pragma unroll
            for (int ct = 0; ct < 4; ++ct) {
                acc1[0][ct] = __builtin_amdgcn_mfma_f32_16x16x32_f16(A0, B1[ct][ks], acc1[0][ct], 0, 0, 0);
                acc1[1][ct] = __builtin_amdgcn_mfma_f32_16x16x32_f16(A1, B1[ct][ks], acc1[1][ct], 0, 0, 0);
            }
        }
        __syncthreads();   // B2: ea reads done before t overwrites union

        // ---- silu -> t frags (scalar f16, ~2-way banks) ----
#pragma unroll
        for (int rt = 0; rt < 2; ++rt)
#pragma unroll
            for (int ct = 0; ct < 4; ++ct)
#pragma unroll
                for (int m = 0; m < 4; ++m) {
                    const int er = wr + rt * 16 + qw * 4 + m;
                    const int c  = wc + ct * 16 + fr;
                    *(f16*)((char*)uni + (size_t)(((c >> 3) * 64 + er) * 16 + (c & 7) * 2)) =
                        (f16)silu_f(acc1[rt][ct][m]);
                }
        __syncthreads();   // B3: t visible

        // ---- stage 2 MFMA: filt = t @ W2 + b2 ----
        f32x4 acc2[2][4];
#pragma unroll
        for (int rt = 0; rt < 2; ++rt)
#pragma unroll
            for (int ct = 0; ct < 4; ++ct)
                acc2[rt][ct] = (f32x4){b2v[ct], b2v[ct], b2v[ct], b2v[ct]};
#pragma unroll
        for (int ks = 0; ks < 4; ++ks) {
            const f16x8 A0 = *(const f16x8*)((char*)uni + (size_t)(((ks * 4 + qw) * 64 + wr + fr) * 16));
            const f16x8 A1 = *(const f16x8*)((char*)uni + (size_t)(((ks * 4 + qw) * 64 + wr + 16 + fr) * 16));
#pragma unroll
            for (int ct = 0; ct < 4; ++ct) {
                acc2[0][ct] = __builtin_amdgcn_mfma_f32_16x16x32_f16(A0, B2[ct][ks], acc2[0][ct], 0, 0, 0);
                acc2[1][ct] = __builtin_amdgcn_mfma_f32_16x16x32_f16(A1, B2[ct][ks], acc2[1][ct], 0, 0, 0);
            }
        }

        // ---- msg = h * filt, in place in h_s (each (er,c) owned by one thread) ----
#pragma unroll
        for (int rt = 0; rt < 2; ++rt)
#pragma unroll
            for (int ct = 0; ct < 4; ++ct)
#pragma unroll
                for (int m = 0; m < 4; ++m) {
                    const int er = wr + rt * 16 + qw * 4 + m;
                    const int c  = wc + ct * 16 + fr;
                    f16* p = &h_s[er * HS_LD + c];
                    *p = (f16)((float)*p * acc2[rt][ct][m]);
                }
        __syncthreads();   // B4: t reads + msg writes done

        // ---- write ea(t+1) frags into union (all threads) ----
        ea_frag_write(uni, j, s, ef0, ef1, ef2, ef3);

        // ---- segmented reduce over sorted dst rows: plain stores ----
        if (tid < 128) {
            for (int r = 0; r < EB; ++r) {
                const int d = dst_s[cur][r];
                const float v = (float)h_s[r * HS_LD + col128];
                if (d != curdst) {
                    out[(size_t)curdst * H + col128] = accv;
                    for (int n = curdst + 1; n < d; ++n) out[(size_t)n * H + col128] = 0.f;
                    curdst = d; accv = 0.f;
                }
                if (d < ne) accv += v;
            }
        }
        __syncthreads();   // B5: ea writes visible; reduce done before next h_s commit

        recP = recN; recN = recN2;
        hP0 = hN0; hP1 = hN1; hP2 = hN2; hP3 = hN3;
        cur ^= 1;
    }

    if (tid < 128 && curdst < ne) {
        out[(size_t)curdst * H + col128] = accv;
        for (int n = curdst + 1; n < ne; ++n) out[(size_t)n * H + col128] = 0.f;
    }
}

// out = x + silu(agg@uW1+ub1)@uW2+ub2 ; agg lives in `out` on entry
__global__ __launch_bounds__(256) void update_kernel(
    const float* __restrict__ x,
    const float* __restrict__ uW1, const float* __restrict__ ub1,
    const float* __restrict__ uW2, const float* __restrict__ ub2,
    float* __restrict__ out, int N)
{
    __shared__ float as[NB][H];
    __shared__ float ts[NB][H];
    const int tid = threadIdx.x;
    const int n0  = blockIdx.x * NB;
    for (int idx = tid; idx < NB * H; idx += 256) {
        int r = idx >> 7, c = idx & (H - 1);
        int n = n0 + r;
        as[r][c] = (n < N) ? out[(size_t)n * H + c] : 0.f;
    }
    __syncthreads();
    const int j  = tid & (H - 1);
    const int rb = (tid >> 7) * 16;
    float acc[16];
    {
        const float b1 = ub1[j];
#pragma unroll
        for (int r = 0; r < 16; ++r) acc[r] = b1;
    }
    for (int kq = 0; kq < H / 4; ++kq) {
        const int k = kq * 4;
        const float w0 = uW1[(k + 0) * H + j];
        const float w1 = uW1[(k + 1) * H + j];
        const float w2 = uW1[(k + 2) * H + j];
        const float w3 = uW1[(k + 3) * H + j];
#pragma unroll
        for (int r = 0; r < 16; ++r) {
            const float4 v = *(const float4*)&as[rb + r][k];
            acc[r] = fmaf(v.x, w0, fmaf(v.y, w1, fmaf(v.z, w2, fmaf(v.w, w3, acc[r]))));
        }
    }
#pragma unroll
    for (int r = 0; r < 16; ++r) ts[rb + r][j] = silu_f(acc[r]);
    __syncthreads();
    {
        const float b2 = ub2[j];
#pragma unroll
        for (int r = 0; r < 16; ++r) acc[r] = b2;
    }
    for (int kq = 0; kq < H / 4; ++kq) {
        const int k = kq * 4;
        const float w0 = uW2[(k + 0) * H + j];
        const float w1 = uW2[(k + 1) * H + j];
        const float w2 = uW2[(k + 2) * H + j];
        const float w3 = uW2[(k + 3) * H + j];
#pragma unroll
        for (int r = 0; r < 16; ++r) {
            const float4 v = *(const float4*)&ts[rb + r][k];
            acc[r] = fmaf(v.x, w0, fmaf(v.y, w1, fmaf(v.z, w2, fmaf(v.w, w3, acc[r]))));
        }
    }
#pragma unroll
    for (int r = 0; r < 16; ++r) {
        int n = n0 + rb + r;
        if (n < N) out[(size_t)n * H + j] = x[(size_t)n * H + j] + acc[r];
    }
}

extern "C" void kernel_launch(void* const* d_in, const int* in_sizes, int n_in,
                              void* d_out, int out_size, void* d_ws, size_t ws_size,
                              hipStream_t stream) {
    const float* x   = (const float*)d_in[0];
    const int*   ei  = (const int*)  d_in[1];
    const float* ea  = (const float*)d_in[2];
    const float* fW1 = (const float*)d_in[3];
    const float* fb1 = (const float*)d_in[4];
    const float* fW2 = (const float*)d_in[5];
    const float* fb2 = (const float*)d_in[6];
    const float* dW  = (const float*)d_in[7];
    const float* db  = (const float*)d_in[8];
    const float* uW1 = (const float*)d_in[9];
    const float* ub1 = (const float*)d_in[10];
    const float* uW2 = (const float*)d_in[11];
    const float* ub2 = (const float*)d_in[12];

    float* out = (float*)d_out;
    const int N = in_sizes[0] / H;
    const int E = in_sizes[1] / 2;
    const int* src = ei;
    const int* dst = ei + E;

    // workspace (~39 MB; >=39 MB proven in R5)
    char* ws = (char*)d_ws;
    size_t off = 0;
    auto alloc = [&](size_t bytes) { void* p = ws + off; off = (off + bytes + 255) & ~(size_t)255; return p; };
    f16*  h      = (f16*) alloc((size_t)N * H * sizeof(f16));
    f16*  Wt1    = (f16*) alloc((size_t)H * K1 * sizeof(f16));
    f16*  Wt2    = (f16*) alloc((size_t)H * H * sizeof(f16));
    int*  counts = (int*) alloc((size_t)N * sizeof(int));
    int*  ofs    = (int*) alloc((size_t)N * sizeof(int));    // becomes scatter cursor
    int*  bsum   = (int*) alloc(256 * sizeof(int));
    int*  nstart = (int*) alloc((size_t)(NBLK + 1) * sizeof(int));
    int*  estart = (int*) alloc((size_t)(NBLK + 1) * sizeof(int));
    int4* rec    = (int4*)alloc((size_t)E * sizeof(int4));

    const int nscan = (N + 255) / 256;   // 196 <= 256

    hipMemsetAsync(counts, 0, (size_t)N * sizeof(int), stream);
    convert_weights_kernel<<<(H * K1 + H * H + 255) / 256, 256, 0, stream>>>(fW1, fW2, Wt1, Wt2);
    compute_h_kernel<<<(N + NB - 1) / NB, 256, 0, stream>>>(x, dW, db, h, N);

    hist_kernel<<<2048, 256, 0, stream>>>(dst, counts, E);
    scan1_kernel<<<nscan, 256, 0, stream>>>(counts, ofs, bsum, N);
    scan2_kernel<<<1, 256, 0, stream>>>(bsum, nscan);
    scan3_kernel<<<nscan, 256, 0, stream>>>(ofs, bsum, N);

    ranges_kernel<<<(NBLK + 256) / 256, 256, 0, stream>>>(ofs, nstart, estart, N, E, NBLK);
    scatter_rec_kernel<<<2048, 256, 0, stream>>>(src, dst, ofs, rec, E);

    edge_fused_kernel<<<NBLK, 256, 0, stream>>>(
        ea, rec, Wt1, Wt2, fb1, fb2, h, out, nstart, estart);

    update_kernel<<<(N + NB - 1) / NB, 256, 0, stream>>>(
        x, uW1, ub1, uW2, ub2, out, N);
}

// Round 7
// 926.368 us; speedup vs baseline: 1.3064x; 1.2223x over previous
//
#include <hip/hip_runtime.h>

#define H    128
#define RBF  50
#define K1   64     // stage-1 K padded 50 -> 64
#define EB   64     // edges per tile
#define NB   32
#define NBLK 1024   // 4 blocks/CU exactly

typedef _Float16 f16;
typedef _Float16 f16x2 __attribute__((ext_vector_type(2)));
typedef _Float16 f16x4 __attribute__((ext_vector_type(4)));
typedef _Float16 f16x8 __attribute__((ext_vector_type(8)));
typedef float    f32x4 __attribute__((ext_vector_type(4)));

#define HS_LD 136   // h_s row stride (f16): 272B, 16B-aligned rows, 2-way banks (free)

__device__ __forceinline__ float silu_f(float a) {
    return a / (1.0f + __expf(-a));
}

// ---------------- CSR build ----------------

__global__ __launch_bounds__(256) void hist_kernel(
    const int* __restrict__ dst, int* __restrict__ counts, int E)
{
    for (int i = blockIdx.x * 256 + threadIdx.x; i < E; i += gridDim.x * 256)
        atomicAdd(&counts[dst[i]], 1);
}

__global__ __launch_bounds__(256) void scan1_kernel(
    const int* __restrict__ counts, int* __restrict__ ofs, int* __restrict__ bsum, int N)
{
    __shared__ int s[256];
    const int t = threadIdx.x;
    const int g = blockIdx.x * 256 + t;
    int v = (g < N) ? counts[g] : 0;
    s[t] = v; __syncthreads();
    for (int off = 1; off < 256; off <<= 1) {
        int u = 0; if (t >= off) u = s[t - off];
        __syncthreads(); s[t] += u; __syncthreads();
    }
    if (g < N) ofs[g] = s[t] - v;
    if (t == 255) bsum[blockIdx.x] = s[255];
}
__global__ __launch_bounds__(256) void scan2_kernel(int* __restrict__ bsum, int nb)
{
    __shared__ int s[256];
    const int t = threadIdx.x;
    int v = (t < nb) ? bsum[t] : 0;
    s[t] = v; __syncthreads();
    for (int off = 1; off < 256; off <<= 1) {
        int u = 0; if (t >= off) u = s[t - off];
        __syncthreads(); s[t] += u; __syncthreads();
    }
    if (t < nb) bsum[t] = s[t] - v;
}
__global__ __launch_bounds__(256) void scan3_kernel(
    int* __restrict__ ofs, const int* __restrict__ bsum, int N)
{
    int g = blockIdx.x * 256 + threadIdx.x;
    if (g < N) ofs[g] += bsum[blockIdx.x];
}

// block ranges cut at node boundaries near b*E/B edges
__global__ __launch_bounds__(256) void ranges_kernel(
    const int* __restrict__ ofs, int* __restrict__ nstart, int* __restrict__ estart,
    int N, int E, int B)
{
    int b = blockIdx.x * 256 + threadIdx.x;
    if (b > B) return;
    if (b == B) { nstart[B] = N; estart[B] = E; return; }
    long long cb = (long long)b * E / B;
    int lo = 0, hi = N;
    while (lo < hi) {
        int mid = (lo + hi) >> 1;
        int val = (mid < N) ? ofs[mid] : E;
        if (val < (int)cb) lo = mid + 1; else hi = mid;
    }
    nstart[b] = lo;
    estart[b] = (lo < N) ? ofs[lo] : E;
}

// rec[pos] = {e, src[e], dst[e], 0} at dst-sorted pos  (destroys cursor=ofs)
__global__ __launch_bounds__(256) void scatter_rec_kernel(
    const int* __restrict__ src, const int* __restrict__ dst,
    int* __restrict__ cursor, int4* __restrict__ rec, int E)
{
    for (int i = blockIdx.x * 256 + threadIdx.x; i < E; i += gridDim.x * 256) {
        int d = dst[i];
        int pos = atomicAdd(&cursor[d], 1);
        rec[pos] = make_int4(i, src[i], d, 0);
    }
}

// ---------------- weight convert + h ----------------

__global__ __launch_bounds__(256) void convert_weights_kernel(
    const float* __restrict__ fW1, const float* __restrict__ fW2,
    f16* __restrict__ Wt1, f16* __restrict__ Wt2)
{
    int i = blockIdx.x * 256 + threadIdx.x;
    if (i < H * K1) {
        int n = i >> 6, k = i & (K1 - 1);
        Wt1[i] = (k < RBF) ? (f16)fW1[k * H + n] : (f16)0.f;
    }
    int j = i - H * K1;
    if (j >= 0 && j < H * H) {
        int n = j >> 7, k = j & (H - 1);
        Wt2[j] = (f16)fW2[k * H + n];
    }
}

__global__ __launch_bounds__(256) void compute_h_kernel(
    const float* __restrict__ x, const float* __restrict__ dW,
    const float* __restrict__ db, f16* __restrict__ h, int N)
{
    __shared__ float xs[NB][H];
    const int tid = threadIdx.x;
    const int n0  = blockIdx.x * NB;
    for (int idx = tid; idx < NB * H; idx += 256) {
        int r = idx >> 7, c = idx & (H - 1);
        int n = n0 + r;
        xs[r][c] = (n < N) ? x[(size_t)n * H + c] : 0.f;
    }
    __syncthreads();
    const int j  = tid & (H - 1);
    const int rb = (tid >> 7) * 16;
    float acc[16];
    const float b = db[j];
#pragma unroll
    for (int r = 0; r < 16; ++r) acc[r] = b;
    for (int kq = 0; kq < H / 4; ++kq) {
        const int k = kq * 4;
        const float w0 = dW[(k + 0) * H + j];
        const float w1 = dW[(k + 1) * H + j];
        const float w2 = dW[(k + 2) * H + j];
        const float w3 = dW[(k + 3) * H + j];
#pragma unroll
        for (int r = 0; r < 16; ++r) {
            const float4 v = *(const float4*)&xs[rb + r][k];
            acc[r] = fmaf(v.x, w0, fmaf(v.y, w1, fmaf(v.z, w2, fmaf(v.w, w3, acc[r]))));
        }
    }
#pragma unroll
    for (int r = 0; r < 16; ++r) {
        int n = n0 + rb + r;
        if (n < N) h[(size_t)n * H + j] = (f16)acc[r];
    }
}

// write one ea row-slice into A-frag-layout LDS: element (row j, col c) lives at
// byte ((c>>3)*64 + j)*16 + (c&7)*2.  Thread (j, s) holds cols {kblk*8.. } per s.
__device__ __forceinline__ void ea_frag_write(
    f16* uni, int j, int s,
    const float4& f0, const float4& f1, const float4& f2, const float2& f3)
{
    char* base = (char*)uni;
    {
        f16x4 v; v[0]=(f16)f0.x; v[1]=(f16)f0.y; v[2]=(f16)f0.z; v[3]=(f16)f0.w;
        *(f16x4*)(base + (size_t)(((0 + (s >> 1)) * 64 + j) * 16 + (s & 1) * 8)) = v;
    }
    {
        f16x4 v; v[0]=(f16)f1.x; v[1]=(f16)f1.y; v[2]=(f16)f1.z; v[3]=(f16)f1.w;
        *(f16x4*)(base + (size_t)(((2 + (s >> 1)) * 64 + j) * 16 + (s & 1) * 8)) = v;
    }
    {
        f16x4 v; v[0]=(f16)f2.x; v[1]=(f16)f2.y; v[2]=(f16)f2.z; v[3]=(f16)f2.w;
        *(f16x4*)(base + (size_t)(((4 + (s >> 1)) * 64 + j) * 16 + (s & 1) * 8)) = v;
    }
    if (s == 0) {
        char* b6 = base + (size_t)((6 * 64 + j) * 16);
        f16x2 v2; v2[0]=(f16)f3.x; v2[1]=(f16)f3.y;
        f16x2 z2 = {};
        *(f16x2*)(b6)      = v2;
        *(f16x2*)(b6 + 4)  = z2;
        *(f16x2*)(b6 + 8)  = z2;
        *(f16x2*)(b6 + 12) = z2;
    } else if (s == 1) {
        f16x8 z8 = {};
        *(f16x8*)(base + (size_t)((7 * 64 + j) * 16)) = z8;
    }
}

// ---------------- fused edge kernel: sector-coalesced gathers, no deep prefetch ----------------
__global__ __launch_bounds__(256, 4) void edge_fused_kernel(
    const float* __restrict__ ea, const int4* __restrict__ rec,
    const f16* __restrict__ Wt1, const f16* __restrict__ Wt2,
    const float* __restrict__ fb1, const float* __restrict__ fb2,
    const f16* __restrict__ h, float* __restrict__ out,
    const int* __restrict__ nstart, const int* __restrict__ estart)
{
    // uni: ea frags [0,8192)B, t frags [0,16384)B (time-shared, barriered)
    __shared__ __align__(16) f16 uni[8192];
    __shared__ __align__(16) f16 h_s[EB * HS_LD];
    __shared__ int dst_s[EB];

    const int tid  = threadIdx.x;
    const int lane = tid & 63;
    const int wv   = tid >> 6;
    const int wr   = (wv >> 1) * 32;
    const int wc   = (wv & 1) * 64;
    const int fr   = lane & 15;
    const int qw   = lane >> 4;
    const int kb   = qw * 8;

    const int j = tid >> 2;   // gather row 0..63
    const int s = tid & 3;    // gather quarter

    // persistent B fragments (may live in AGPRs; no prefetch pressure now)
    f16x8 B1[4][2];
    f16x8 B2[4][4];
    float b1v[4], b2v[4];
#pragma unroll
    for (int ct = 0; ct < 4; ++ct) {
        const int col = wc + ct * 16 + fr;
#pragma unroll
        for (int ks = 0; ks < 2; ++ks)
            B1[ct][ks] = *(const f16x8*)&Wt1[col * K1 + ks * 32 + kb];
#pragma unroll
        for (int ks = 0; ks < 4; ++ks)
            B2[ct][ks] = *(const f16x8*)&Wt2[col * H + ks * 32 + kb];
        b1v[ct] = fb1[col];
        b2v[ct] = fb2[col];
    }

    const int ns = nstart[blockIdx.x], ne = nstart[blockIdx.x + 1];
    const int e0 = estart[blockIdx.x], e1 = estart[blockIdx.x + 1];

    if (e0 >= e1) {   // no edges: zero own node range
        for (int idx = tid; idx < (ne - ns) * H; idx += 256)
            out[(size_t)ns * H + idx] = 0.f;
        return;
    }

    const int col128 = tid & 127;
    int   curdst = ns;
    float accv   = 0.f;

    // prime rec for tile 0 (clamped)
    int4 recP;
    {
        int idx = e0 + j; idx = (idx < e1) ? idx : (e1 - 1);
        recP = rec[idx];
    }

    for (int tb = e0; tb < e1; tb += EB) {
        // ---- prefetch next tile's rec row (4 VGPRs only) ----
        int4 recN;
        {
            int idx = tb + EB + j; idx = (idx < e1) ? idx : (e1 - 1);
            recN = rec[idx];
        }

        // ---- stage: sector-coalesced h + ea gathers straight to LDS ----
        {
            const f16* hp = h + (size_t)recP.y * H + s * 8;
            const f16x8 h0 = *(const f16x8*)(hp);
            const f16x8 h1 = *(const f16x8*)(hp + 32);
            const f16x8 h2 = *(const f16x8*)(hp + 64);
            const f16x8 h3 = *(const f16x8*)(hp + 96);
            const float* ep = ea + (size_t)recP.x * RBF + s * 4;
            const float4 ef0 = *(const float4*)(ep);
            const float4 ef1 = *(const float4*)(ep + 16);
            const float4 ef2 = *(const float4*)(ep + 32);
            float2 ef3 = {};
            if (s == 0) ef3 = *(const float2*)(ea + (size_t)recP.x * RBF + 48);

            *(f16x8*)&h_s[j * HS_LD +  0 + s * 8] = h0;
            *(f16x8*)&h_s[j * HS_LD + 32 + s * 8] = h1;
            *(f16x8*)&h_s[j * HS_LD + 64 + s * 8] = h2;
            *(f16x8*)&h_s[j * HS_LD + 96 + s * 8] = h3;
            ea_frag_write(uni, j, s, ef0, ef1, ef2, ef3);
            if (s == 0) dst_s[j] = (tb + j < e1) ? recP.z : ne;
        }
        __syncthreads();   // B1: ea + h_s + dst_s visible

        // ---- stage 1 MFMA: t = ea @ W1 + b1 ----
        f32x4 acc1[2][4];
#pragma unroll
        for (int rt = 0; rt < 2; ++rt)
#pragma unroll
            for (int ct = 0; ct < 4; ++ct)
                acc1[rt][ct] = (f32x4){b1v[ct], b1v[ct], b1v[ct], b1v[ct]};
#pragma unroll
        for (int ks = 0; ks < 2; ++ks) {
            const f16x8 A0 = *(const f16x8*)((char*)uni + (size_t)(((ks * 4 + qw) * 64 + wr + fr) * 16));
            const f16x8 A1 = *(const f16x8*)((char*)uni + (size_t)(((ks * 4 + qw) * 64 + wr + 16 + fr) * 16));
#pragma unroll
            for (int ct = 0; ct < 4; ++ct) {
                acc1[0][ct] = __builtin_amdgcn_mfma_f32_16x16x32_f16(A0, B1[ct][ks], acc1[0][ct], 0, 0, 0);
                acc1[1][ct] = __builtin_amdgcn_mfma_f32_16x16x32_f16(A1, B1[ct][ks], acc1[1][ct], 0, 0, 0);
            }
        }
        __syncthreads();   // B2: ea reads done before t overwrites union

        // ---- silu -> t frags ----
#pragma unroll
        for (int rt = 0; rt < 2; ++rt)
#pragma unroll
            for (int ct = 0; ct < 4; ++ct)
#pragma unroll
                for (int m = 0; m < 4; ++m) {
                    const int er = wr + rt * 16 + qw * 4 + m;
                    const int c  = wc + ct * 16 + fr;
                    *(f16*)((char*)uni + (size_t)(((c >> 3) * 64 + er) * 16 + (c & 7) * 2)) =
                        (f16)silu_f(acc1[rt][ct][m]);
                }
        __syncthreads();   // B3: t visible

        // ---- stage 2 MFMA: filt = t @ W2 + b2 ----
        f32x4 acc2[2][4];
#pragma unroll
        for (int rt = 0; rt < 2; ++rt)
#pragma unroll
            for (int ct = 0; ct < 4; ++ct)
                acc2[rt][ct] = (f32x4){b2v[ct], b2v[ct], b2v[ct], b2v[ct]};
#pragma unroll
        for (int ks = 0; ks < 4; ++ks) {
            const f16x8 A0 = *(const f16x8*)((char*)uni + (size_t)(((ks * 4 + qw) * 64 + wr + fr) * 16));
            const f16x8 A1 = *(const f16x8*)((char*)uni + (size_t)(((ks * 4 + qw) * 64 + wr + 16 + fr) * 16));
#pragma unroll
            for (int ct = 0; ct < 4; ++ct) {
                acc2[0][ct] = __builtin_amdgcn_mfma_f32_16x16x32_f16(A0, B2[ct][ks], acc2[0][ct], 0, 0, 0);
                acc2[1][ct] = __builtin_amdgcn_mfma_f32_16x16x32_f16(A1, B2[ct][ks], acc2[1][ct], 0, 0, 0);
            }
        }

        // ---- msg = h * filt, in place in h_s (each (er,c) owned by one thread) ----
#pragma unroll
        for (int rt = 0; rt < 2; ++rt)
#pragma unroll
            for (int ct = 0; ct < 4; ++ct)
#pragma unroll
                for (int m = 0; m < 4; ++m) {
                    const int er = wr + rt * 16 + qw * 4 + m;
                    const int c  = wc + ct * 16 + fr;
                    f16* p = &h_s[er * HS_LD + c];
                    *p = (f16)((float)*p * acc2[rt][ct][m]);
                }
        __syncthreads();   // B4: msg writes visible

        // ---- segmented reduce over sorted dst rows: plain stores ----
        if (tid < 128) {
            for (int r = 0; r < EB; ++r) {
                const int d = dst_s[r];
                const float v = (float)h_s[r * HS_LD + col128];
                if (d != curdst) {
                    out[(size_t)curdst * H + col128] = accv;
                    for (int n = curdst + 1; n < d; ++n) out[(size_t)n * H + col128] = 0.f;
                    curdst = d; accv = 0.f;
                }
                if (d < ne) accv += v;
            }
        }
        __syncthreads();   // B5: reduce done before next tile's staging

        recP = recN;
    }

    if (tid < 128 && curdst < ne) {
        out[(size_t)curdst * H + col128] = accv;
        for (int n = curdst + 1; n < ne; ++n) out[(size_t)n * H + col128] = 0.f;
    }
}

// out = x + silu(agg@uW1+ub1)@uW2+ub2 ; agg lives in `out` on entry
__global__ __launch_bounds__(256) void update_kernel(
    const float* __restrict__ x,
    const float* __restrict__ uW1, const float* __restrict__ ub1,
    const float* __restrict__ uW2, const float* __restrict__ ub2,
    float* __restrict__ out, int N)
{
    __shared__ float as[NB][H];
    __shared__ float ts[NB][H];
    const int tid = threadIdx.x;
    const int n0  = blockIdx.x * NB;
    for (int idx = tid; idx < NB * H; idx += 256) {
        int r = idx >> 7, c = idx & (H - 1);
        int n = n0 + r;
        as[r][c] = (n < N) ? out[(size_t)n * H + c] : 0.f;
    }
    __syncthreads();
    const int j  = tid & (H - 1);
    const int rb = (tid >> 7) * 16;
    float acc[16];
    {
        const float b1 = ub1[j];
#pragma unroll
        for (int r = 0; r < 16; ++r) acc[r] = b1;
    }
    for (int kq = 0; kq < H / 4; ++kq) {
        const int k = kq * 4;
        const float w0 = uW1[(k + 0) * H + j];
        const float w1 = uW1[(k + 1) * H + j];
        const float w2 = uW1[(k + 2) * H + j];
        const float w3 = uW1[(k + 3) * H + j];
#pragma unroll
        for (int r = 0; r < 16; ++r) {
            const float4 v = *(const float4*)&as[rb + r][k];
            acc[r] = fmaf(v.x, w0, fmaf(v.y, w1, fmaf(v.z, w2, fmaf(v.w, w3, acc[r]))));
        }
    }
#pragma unroll
    for (int r = 0; r < 16; ++r) ts[rb + r][j] = silu_f(acc[r]);
    __syncthreads();
    {
        const float b2 = ub2[j];
#pragma unroll
        for (int r = 0; r < 16; ++r) acc[r] = b2;
    }
    for (int kq = 0; kq < H / 4; ++kq) {
        const int k = kq * 4;
        const float w0 = uW2[(k + 0) * H + j];
        const float w1 = uW2[(k + 1) * H + j];
        const float w2 = uW2[(k + 2) * H + j];
        const float w3 = uW2[(k + 3) * H + j];
#pragma unroll
        for (int r = 0; r < 16; ++r) {
            const float4 v = *(const float4*)&ts[rb + r][k];
            acc[r] = fmaf(v.x, w0, fmaf(v.y, w1, fmaf(v.z, w2, fmaf(v.w, w3, acc[r]))));
        }
    }
#pragma unroll
    for (int r = 0; r < 16; ++r) {
        int n = n0 + rb + r;
        if (n < N) out[(size_t)n * H + j] = x[(size_t)n * H + j] + acc[r];
    }
}

extern "C" void kernel_launch(void* const* d_in, const int* in_sizes, int n_in,
                              void* d_out, int out_size, void* d_ws, size_t ws_size,
                              hipStream_t stream) {
    const float* x   = (const float*)d_in[0];
    const int*   ei  = (const int*)  d_in[1];
    const float* ea  = (const float*)d_in[2];
    const float* fW1 = (const float*)d_in[3];
    const float* fb1 = (const float*)d_in[4];
    const float* fW2 = (const float*)d_in[5];
    const float* fb2 = (const float*)d_in[6];
    const float* dW  = (const float*)d_in[7];
    const float* db  = (const float*)d_in[8];
    const float* uW1 = (const float*)d_in[9];
    const float* ub1 = (const float*)d_in[10];
    const float* uW2 = (const float*)d_in[11];
    const float* ub2 = (const float*)d_in[12];

    float* out = (float*)d_out;
    const int N = in_sizes[0] / H;
    const int E = in_sizes[1] / 2;
    const int* src = ei;
    const int* dst = ei + E;

    // workspace (~39 MB; proven available)
    char* ws = (char*)d_ws;
    size_t off = 0;
    auto alloc = [&](size_t bytes) { void* p = ws + off; off = (off + bytes + 255) & ~(size_t)255; return p; };
    f16*  h      = (f16*) alloc((size_t)N * H * sizeof(f16));
    f16*  Wt1    = (f16*) alloc((size_t)H * K1 * sizeof(f16));
    f16*  Wt2    = (f16*) alloc((size_t)H * H * sizeof(f16));
    int*  counts = (int*) alloc((size_t)N * sizeof(int));
    int*  ofs    = (int*) alloc((size_t)N * sizeof(int));    // becomes scatter cursor
    int*  bsum   = (int*) alloc(256 * sizeof(int));
    int*  nstart = (int*) alloc((size_t)(NBLK + 1) * sizeof(int));
    int*  estart = (int*) alloc((size_t)(NBLK + 1) * sizeof(int));
    int4* rec    = (int4*)alloc((size_t)E * sizeof(int4));

    const int nscan = (N + 255) / 256;   // 196 <= 256

    hipMemsetAsync(counts, 0, (size_t)N * sizeof(int), stream);
    convert_weights_kernel<<<(H * K1 + H * H + 255) / 256, 256, 0, stream>>>(fW1, fW2, Wt1, Wt2);
    compute_h_kernel<<<(N + NB - 1) / NB, 256, 0, stream>>>(x, dW, db, h, N);

    hist_kernel<<<2048, 256, 0, stream>>>(dst, counts, E);
    scan1_kernel<<<nscan, 256, 0, stream>>>(counts, ofs, bsum, N);
    scan2_kernel<<<1, 256, 0, stream>>>(bsum, nscan);
    scan3_kernel<<<nscan, 256, 0, stream>>>(ofs, bsum, N);

    ranges_kernel<<<(NBLK + 256) / 256, 256, 0, stream>>>(ofs, nstart, estart, N, E, NBLK);
    scatter_rec_kernel<<<2048, 256, 0, stream>>>(src, dst, ofs, rec, E);

    edge_fused_kernel<<<NBLK, 256, 0, stream>>>(
        ea, rec, Wt1, Wt2, fb1, fb2, h, out, nstart, estart);

    update_kernel<<<(N + NB - 1) / NB, 256, 0, stream>>>(
        x, uW1, ub1, uW2, ub2, out, N);
}